// Round 16
// baseline (39.874 us; speedup 1.0000x reference)
//
#include <hip/hip_runtime.h>
#include <hip/hip_bf16.h>

namespace {
constexpr int kB = 2, kW = 5, kS = 5, kQ = 75, kC = 64, kHW = 441;
constexpr int kNP = 448;   // support positions padded (14 * 32)
constexpr int kMP = 448;   // query positions padded
constexpr int kCHUNK = 112;
constexpr int kLDT = 65;
constexpr int kTiles = kB * kQ * kW;              // 750
constexpr int kThreads = 448;                     // 7 waves, 2 col-tiles each
constexpr int kWaves = 7;
constexpr int kGrid = 512;                        // exactly 2 blocks/CU, all resident
constexpr int kPrepGrid = 8 * 81;

typedef short bf16x8 __attribute__((ext_vector_type(8)));
typedef float f32x16 __attribute__((ext_vector_type(16)));
typedef __attribute__((address_space(3))) unsigned int lds_u32;
typedef const __attribute__((address_space(1))) unsigned int gbl_u32;
}

// ---- prep (R15-validated, unchanged): XCD-co-located shot-mean + L2-norm + transpose ----
__global__ __launch_bounds__(256) void prep_k(const float* __restrict__ sup,
                                              const float* __restrict__ qry,
                                              unsigned short* __restrict__ snT,
                                              unsigned short* __restrict__ qnT) {
  __shared__ float img_t[kCHUNK * kLDT];
  __shared__ float inv[kCHUNK];
  const int tid = threadIdx.x;
  const int x = blockIdx.x & 7;
  const int j = blockIdx.x >> 3;

  const int start0 = (x < 6) ? 94 * x : 564 + 93 * (x - 6);
  const int start1 = (x + 1 < 6) ? 94 * (x + 1) : 564 + 93 * (x + 1 - 6);
  const int lo = (start0 + 4) / 5, hi = (start1 + 4) / 5;
  const int nq = 4 * (hi - lo);

  bool is_sup;
  int bw = 0, bq = 0, chunk;
  if (j < nq) {
    is_sup = false;
    bq = lo + (j >> 2);
    chunk = j & 3;
  } else {
    int js = j - nq;
    if (js >= 5) return;
    is_sup = true;
    int u = x + 8 * js;
    bw = u >> 2;
    chunk = u & 3;
  }

  const int m0 = chunk * kCHUNK;
  const int mcnt = min(kCHUNK, kHW - m0);
  unsigned short* dst;

  if (is_sup) {
    const float* base = sup + (size_t)bw * kS * kC * kHW;
    for (int i = tid; i < kC * kCHUNK; i += 256) {
      int c = i / kCHUNK, mm = i % kCHUNK;
      float v = 0.f;
      if (mm < mcnt) {
        const float* p = base + (size_t)c * kHW + m0 + mm;
        float s = 0.f;
#pragma unroll
        for (int k = 0; k < kS; ++k) s += p[(size_t)k * kC * kHW];
        v = s * (1.f / kS);
      }
      img_t[mm * kLDT + c] = v;
    }
    dst = snT + (size_t)bw * kNP * kC;
  } else {
    const float* base = qry + (size_t)bq * kC * kHW;
    for (int i = tid; i < kC * kCHUNK; i += 256) {
      int c = i / kCHUNK, mm = i % kCHUNK;
      img_t[mm * kLDT + c] = (mm < mcnt) ? base[(size_t)c * kHW + m0 + mm] : 0.f;
    }
    dst = qnT + (size_t)bq * kMP * kC;
  }
  __syncthreads();

  if (tid < kCHUNK) {
    float ss = 0.f;
#pragma unroll
    for (int c = 0; c < kC; ++c) { float v = img_t[tid * kLDT + c]; ss += v * v; }
    inv[tid] = 1.f / fmaxf(sqrtf(ss), 1e-12f);
  }
  __syncthreads();

  for (int i8 = tid; i8 < kCHUNK * 8; i8 += 256) {
    int m = i8 >> 3, c8 = (i8 & 7) * 8;
    float sc = inv[m];
    union { unsigned short u[8]; uint4 v; } pk;
#pragma unroll
    for (int jj = 0; jj < 8; ++jj) {
      __hip_bfloat16 o = __float2bfloat16(img_t[m * kLDT + c8 + jj] * sc);
      pk.u[jj] = *reinterpret_cast<unsigned short*>(&o);
    }
    *reinterpret_cast<uint4*>(dst + ((size_t)(m0 + m) * kC + c8)) = pk.v;
  }
}

// ---- max helpers (validated; no inline asm — R12 lesson) ----
__device__ __forceinline__ float max16_v(const f32x16& a) {
  float m0 = fmaxf(fmaxf(a[0], a[1]), a[2]);
  float m1 = fmaxf(fmaxf(a[3], a[4]), a[5]);
  float m2 = fmaxf(fmaxf(a[6], a[7]), a[8]);
  float m3 = fmaxf(fmaxf(a[9], a[10]), a[11]);
  float m4 = fmaxf(fmaxf(a[12], a[13]), a[14]);
  return fmaxf(fmaxf(fmaxf(m0, m1), m2), fmaxf(fmaxf(m3, m4), a[15]));
}
__device__ __forceinline__ float max12_v(const f32x16& a) {
  float m0 = fmaxf(fmaxf(a[0], a[1]), a[2]);
  float m1 = fmaxf(fmaxf(a[3], a[4]), a[5]);
  float m2 = fmaxf(fmaxf(a[6], a[7]), a[8]);
  float m3 = fmaxf(fmaxf(a[9], a[10]), a[11]);
  return fmaxf(fmaxf(m0, m1), fmaxf(m2, m3));
}

// stage one 224-row half (4 rounds x 448 lanes x 16B), pre-swizzled source
__device__ __forceinline__ void stage_half(const unsigned short* sb, int h,
                                           unsigned short* dstbuf, int tid) {
  const char* sbase = (const char*)sb + (size_t)h * 1792 * 16;
#pragma unroll
  for (int it = 0; it < 4; ++it) {
    int L = it * kThreads + tid;
    int srcj = (L & ~7) | ((L & 7) ^ ((L >> 3) & 7));
    __builtin_amdgcn_global_load_lds((gbl_u32*)(sbase + ((size_t)srcj << 4)),
                                     (lds_u32*)((char*)dstbuf + ((size_t)L << 4)), 16, 0, 0);
  }
}

// 7 sub-tiles from a 224-row buffer; TAIL masks sub-tile 6 (rows 441..447 pad)
template <bool TAIL>
__device__ __forceinline__ void compute_half7(const unsigned short* As,
                                              const bf16x8 bf[2][4],
                                              int lane, float rm[2]) {
  const int lh = lane >> 5;
  const int lm = lane & 31;
  // hoisted swizzled addresses: n&7 == lm&7 invariant across sub-tiles
  const unsigned short* p0 = As + ((size_t)(lm * 8 + ((0 * 2 + lh) ^ (lm & 7))) << 3);
  const unsigned short* p1 = As + ((size_t)(lm * 8 + ((1 * 2 + lh) ^ (lm & 7))) << 3);
  const unsigned short* p2 = As + ((size_t)(lm * 8 + ((2 * 2 + lh) ^ (lm & 7))) << 3);
  const unsigned short* p3 = As + ((size_t)(lm * 8 + ((3 * 2 + lh) ^ (lm & 7))) << 3);
  f32x16 z;
#pragma unroll
  for (int r = 0; r < 16; ++r) z[r] = 0.f;

#pragma unroll 1   // full unroll spills (R6 lesson)
  for (int sub = 0; sub < 7; ++sub) {
    const size_t so = (size_t)sub * 32 * kC;   // 2048 ushorts per sub-tile
    bf16x8 af[4];
    af[0] = *reinterpret_cast<const bf16x8*>(p0 + so);
    af[1] = *reinterpret_cast<const bf16x8*>(p1 + so);
    af[2] = *reinterpret_cast<const bf16x8*>(p2 + so);
    af[3] = *reinterpret_cast<const bf16x8*>(p3 + so);
    if (!TAIL || sub < 6) {
#pragma unroll
      for (int ct = 0; ct < 2; ++ct) {
        f32x16 acc = z;
#pragma unroll
        for (int kk = 0; kk < 4; ++kk)
          acc = __builtin_amdgcn_mfma_f32_32x32x16_bf16(af[kk], bf[ct][kk], acc, 0, 0, 0);
        rm[ct] = fmaxf(rm[ct], max16_v(acc));
      }
    } else {
      // rows 416..447; valid < 441 -> tile row <= 24.
      // row = (r&3)+8*(r>>2)+4*lh: lh0 invalid regs {13,14,15}, lh1 invalid {12..15}
#pragma unroll
      for (int ct = 0; ct < 2; ++ct) {
        f32x16 acc = z;
#pragma unroll
        for (int kk = 0; kk < 4; ++kk)
          acc = __builtin_amdgcn_mfma_f32_32x32x16_bf16(af[kk], bf[ct][kk], acc, 0, 0, 0);
        float t = max12_v(acc);
        if (lh == 0) t = fmaxf(t, acc[12]);  // row 24 still valid
        rm[ct] = fmaxf(rm[ct], t);
      }
    }
  }
}

// ---- main: persistent 512-block grid (2/CU, all resident), 1-2 tiles/block
//      (balanced via bit0^bit5 slot parity), cross-tile double-buffered halves,
//      counted vmcnt(4) entry waits, raw 2-barrier phases — pipeline never
//      restarts between tiles. ----
__global__ __launch_bounds__(kThreads) void dn4_main_k(const unsigned short* __restrict__ qnT,
                                                       const unsigned short* __restrict__ snT,
                                                       float* __restrict__ out) {
  __shared__ __align__(16) unsigned short As[2][224 * kC];  // 2 x 28672 B
  __shared__ float part[kWaves];
  const int tid = threadIdx.x;

  const int xcd = blockIdx.x & 7;     // dispatch round-robin (m09/m157)
  const int s = blockIdx.x >> 3;      // slot 0..63 within XCD
  const int cnt = (xcd < 6) ? 94 : 93;
  const int base = (xcd < 6) ? 94 * xcd : 564 + 93 * (xcd - 6);
  const int idx0 = base + s;
  // second-tile rank: f(s)=bit0^bit5 stripes 2-tile blocks across either
  // plausible block->CU pairing ((s,s+32) or (2k,2k+1))
  const int rank = (s < 32) ? ((s & 1) ? (s >> 1) : -1)
                            : (((s & 1) == 0) ? 16 + ((s - 32) >> 1) : -1);
  const bool has2 = (rank >= 0) && (64 + rank < cnt);
  const int idx1 = has2 ? base + 64 + rank : idx0;
  const int P = has2 ? 4 : 2;

  const int lane = tid & 63;
  const int lh = lane >> 5;
  const int lm = lane & 31;
  const int wid = tid >> 6;
  const int ct0 = wid * 2;

  // tile0 pointers + bf load + first stage
  const unsigned short* sb0 =
      snT + (size_t)((idx0 / (kQ * kW)) * kW + (idx0 % kW)) * kNP * kC;
  const unsigned short* qb0 = qnT + (size_t)(idx0 / kW) * kMP * kC;

  bf16x8 bf[2][4];
#pragma unroll
  for (int ct = 0; ct < 2; ++ct) {
    int m = (ct0 + ct) * 32 + lm;
#pragma unroll
    for (int kk = 0; kk < 4; ++kk)
      bf[ct][kk] = *reinterpret_cast<const bf16x8*>(qb0 + (size_t)m * kC + kk * 16 + lh * 8);
  }
  stage_half(sb0, 0, As[0], tid);

  float rm[2] = {-INFINITY, -INFINITY};

#pragma unroll 1
  for (int ph = 0; ph < P; ++ph) {
    const int cur = ph & 1;
    const int idx = (ph >> 1) ? idx1 : idx0;

    if (ph == 2) {  // tile switch: reload bf BEFORE the stage (vmcnt ordering)
      const unsigned short* qb1 = qnT + (size_t)(idx1 / kW) * kMP * kC;
#pragma unroll
      for (int ct = 0; ct < 2; ++ct) {
        int m = (ct0 + ct) * 32 + lm;
#pragma unroll
        for (int kk = 0; kk < 4; ++kk)
          bf[ct][kk] = *reinterpret_cast<const bf16x8*>(qb1 + (size_t)m * kC + kk * 16 + lh * 8);
      }
    }

    if (ph + 1 < P) {
      const int nidx = ((ph + 1) >> 1) ? idx1 : idx0;
      const unsigned short* sbn =
          snT + (size_t)((nidx / (kQ * kW)) * kW + (nidx % kW)) * kNP * kC;
      stage_half(sbn, (ph + 1) & 1, As[cur ^ 1], tid);
      asm volatile("s_waitcnt vmcnt(4)" ::: "memory");  // buf[cur] + bf landed
    } else {
      asm volatile("s_waitcnt vmcnt(0)" ::: "memory");
    }
    __builtin_amdgcn_sched_barrier(0);
    __builtin_amdgcn_s_barrier();       // buf[cur] ready for all waves
    __builtin_amdgcn_sched_barrier(0);

    if ((ph & 1) == 0) {
      compute_half7<false>(As[cur], bf, lane, rm);
      __builtin_amdgcn_s_barrier();     // end of phase: buf[cur] safe to overwrite
      __builtin_amdgcn_sched_barrier(0);
    } else {
      compute_half7<true>(As[cur], bf, lane, rm);
      // tile finished: reduce + store
      float sm = fmaxf(rm[0], __shfl_xor(rm[0], 32, 64)) +
                 fmaxf(rm[1], __shfl_xor(rm[1], 32, 64));
#pragma unroll
      for (int off = 1; off < 32; off <<= 1) sm += __shfl_xor(sm, off, 64);
      if (lane == 0) part[wid] = sm;
      asm volatile("s_waitcnt lgkmcnt(0)" ::: "memory");
      __builtin_amdgcn_sched_barrier(0);
      __builtin_amdgcn_s_barrier();     // part visible + end of phase
      __builtin_amdgcn_sched_barrier(0);
      if (tid == 0) {
        float t = 0.f;
#pragma unroll
        for (int v = 0; v < kWaves; ++v) t += part[v];
        out[idx] = t;
      }
      rm[0] = -INFINITY; rm[1] = -INFINITY;
    }
  }
}

extern "C" void kernel_launch(void* const* d_in, const int* in_sizes, int n_in,
                              void* d_out, int out_size, void* d_ws, size_t ws_size,
                              hipStream_t stream) {
  const float* sup = (const float*)d_in[0];
  const float* qry = (const float*)d_in[2];
  float* out = (float*)d_out;

  unsigned short* snT = (unsigned short*)d_ws;                 // 573,440 B
  unsigned short* qnT = snT + (size_t)kB * kW * kNP * kC;      // 8,601,600 B

  prep_k<<<kPrepGrid, 256, 0, stream>>>(sup, qry, snT, qnT);
  dn4_main_k<<<kGrid, kThreads, 0, stream>>>(qnT, snT, out);
}